// Round 1
// baseline (1383.541 us; speedup 1.0000x reference)
//
#include <hip/hip_runtime.h>
#include <hip/hip_bf16.h>

// PairwiseInteract: 8 MLPs (2->50->50->50->20) over 1024x1024 pairs, reduce over
// actors, then 2 head MLPs (20->50->1).
// Strategy: fp32 vector pipe (no fp32 MFMA on CDNA4). One thread per pair;
// activations live in a thread-private LDS column ([k][tid] layout: lanes
// contiguous -> conflict-free); hn[50] in registers (o-loop unrolled, k-loop
// rolled). Weights are wave-uniform -> SGPR operands via s_load.

#define NOBJ 1024
#define H 50   // hidden width
#define F 20   // force dim

__global__ __launch_bounds__(256)
void pair_kernel(const float* __restrict__ obj0, const float* __restrict__ obj1,
                 const float* __restrict__ prev0, const float* __restrict__ prev1,
                 const float* __restrict__ gW0, const float* __restrict__ gb0,
                 const float* __restrict__ gW1, const float* __restrict__ gb1,
                 const float* __restrict__ gW2, const float* __restrict__ gb2,
                 const float* __restrict__ gW3, const float* __restrict__ gb3,
                 float* __restrict__ forces)
{
    // thread-private activation columns: hbuf[k][tid], lanes contiguous
    __shared__ float hbuf[H * 256];
    const int lt = threadIdx.y * 64 + threadIdx.x;

    const int m = blockIdx.y;          // module 0..7 (wave-uniform)
    const int a = m >> 1;              // actor class
    const int c = m & 1;               // actee class
    const int i = blockIdx.x * 4 + threadIdx.y;   // actee object (wave-uniform)
    const int jhalf = blockIdx.z;      // split j-range for load balance

    const float* actor = (a == 0) ? obj0 : (a == 1) ? obj1 : (a == 2) ? prev0 : prev1;
    const float* actee = (c == 0) ? obj0 : obj1;
    const float av = actee[i];

    const float* __restrict__ w0 = gW0 + m * 2 * H;
    const float* __restrict__ b0 = gb0 + m * H;
    const float* __restrict__ w1 = gW1 + m * H * H;
    const float* __restrict__ b1 = gb1 + m * H;
    const float* __restrict__ w2 = gW2 + m * H * H;
    const float* __restrict__ b2 = gb2 + m * H;
    const float* __restrict__ w3 = gW3 + m * H * F;
    const float* __restrict__ b3 = gb3 + m * F;

    float acc[F];
#pragma unroll
    for (int f = 0; f < F; ++f) acc[f] = 0.f;

    const int jbeg = jhalf * 512;
    for (int j0 = jbeg; j0 < jbeg + 512; j0 += 64) {
        const float xa = actor[j0 + threadIdx.x];

        // Layer 0: 2 -> 50, write relu to LDS
#pragma unroll
        for (int o = 0; o < H; ++o) {
            float v = fmaf(xa, w0[o], fmaf(av, w0[H + o], b0[o]));
            hbuf[o * 256 + lt] = fmaxf(v, 0.f);
        }

        // Layer 1: 50 -> 50
        float hn[H];
#pragma unroll
        for (int o = 0; o < H; ++o) hn[o] = b1[o];
#pragma unroll 1
        for (int k = 0; k < H; ++k) {
            const float hk = hbuf[k * 256 + lt];
            const float* wr = w1 + k * H;
#pragma unroll
            for (int o = 0; o < H; ++o) hn[o] = fmaf(hk, wr[o], hn[o]);
        }
#pragma unroll
        for (int o = 0; o < H; ++o) hbuf[o * 256 + lt] = fmaxf(hn[o], 0.f);

        // Layer 2: 50 -> 50
#pragma unroll
        for (int o = 0; o < H; ++o) hn[o] = b2[o];
#pragma unroll 1
        for (int k = 0; k < H; ++k) {
            const float hk = hbuf[k * 256 + lt];
            const float* wr = w2 + k * H;
#pragma unroll
            for (int o = 0; o < H; ++o) hn[o] = fmaf(hk, wr[o], hn[o]);
        }
#pragma unroll
        for (int o = 0; o < H; ++o) hbuf[o * 256 + lt] = fmaxf(hn[o], 0.f);

        // Layer 3: 50 -> 20, accumulate over pairs (bias folded in at the end)
#pragma unroll 1
        for (int k = 0; k < H; ++k) {
            const float hk = hbuf[k * 256 + lt];
            const float* wr = w3 + k * F;
#pragma unroll
            for (int f = 0; f < F; ++f) acc[f] = fmaf(hk, wr[f], acc[f]);
        }
    }

    // wave (64-lane) butterfly reduction of acc over actors j
#pragma unroll
    for (int f = 0; f < F; ++f) {
        float v = acc[f];
#pragma unroll
        for (int mask = 32; mask >= 1; mask >>= 1) v += __shfl_xor(v, mask, 64);
        acc[f] = v;
    }
    if (threadIdx.x == 0) {
        float* dst = forces + (c * NOBJ + i) * F;
#pragma unroll
        for (int f = 0; f < F; ++f)
            atomicAdd(dst + f, acc[f] + 512.f * b3[f]);   // 512 pairs of bias per wave
    }
}

__global__ __launch_bounds__(256)
void apply_kernel(const float* __restrict__ forces,
                  const float* __restrict__ aW0, const float* __restrict__ ab0,
                  const float* __restrict__ aW1, const float* __restrict__ ab1,
                  float* __restrict__ out)
{
    const int t = blockIdx.x * 256 + threadIdx.x;   // 0..2047
    const int c = t >> 10;                          // wave-uniform (1024 % 64 == 0)
    const int i = t & 1023;

    const float* f = forces + (c * NOBJ + i) * F;
    float fin[F];
#pragma unroll
    for (int k = 0; k < F; ++k) fin[k] = f[k];

    const float* __restrict__ w0 = aW0 + c * F * H;   // (20,50)
    const float* __restrict__ b0 = ab0 + c * H;
    const float* __restrict__ w1 = aW1 + c * H;       // (50,1)
    float pred = ab1[c];
#pragma unroll
    for (int o = 0; o < H; ++o) {
        float s = b0[o];
#pragma unroll
        for (int k = 0; k < F; ++k) s = fmaf(fin[k], w0[k * H + o], s);
        pred = fmaf(fmaxf(s, 0.f), w1[o], pred);
    }
    out[t] = pred;
}

extern "C" void kernel_launch(void* const* d_in, const int* in_sizes, int n_in,
                              void* d_out, int out_size, void* d_ws, size_t ws_size,
                              hipStream_t stream) {
    const float* obj0  = (const float*)d_in[0];
    const float* obj1  = (const float*)d_in[1];
    const float* prev0 = (const float*)d_in[2];
    const float* prev1 = (const float*)d_in[3];
    const float* gW0 = (const float*)d_in[4];
    const float* gb0 = (const float*)d_in[5];
    const float* gW1 = (const float*)d_in[6];
    const float* gb1 = (const float*)d_in[7];
    const float* gW2 = (const float*)d_in[8];
    const float* gb2 = (const float*)d_in[9];
    const float* gW3 = (const float*)d_in[10];
    const float* gb3 = (const float*)d_in[11];
    const float* aW0 = (const float*)d_in[12];
    const float* ab0 = (const float*)d_in[13];
    const float* aW1 = (const float*)d_in[14];
    const float* ab1 = (const float*)d_in[15];

    float* forces = (float*)d_ws;   // [2][1024][20] fp32 partial-force accumulator
    hipMemsetAsync(forces, 0, 2 * NOBJ * F * sizeof(float), stream);

    dim3 g1(NOBJ / 4, 8, 2);   // i-tiles x modules x j-halves
    dim3 b1(64, 4, 1);
    pair_kernel<<<g1, b1, 0, stream>>>(obj0, obj1, prev0, prev1,
                                       gW0, gb0, gW1, gb1, gW2, gb2, gW3, gb3,
                                       forces);

    apply_kernel<<<8, 256, 0, stream>>>(forces, aW0, ab0, aW1, ab1, (float*)d_out);
}

// Round 2
// 617.836 us; speedup vs baseline: 2.2393x; 2.2393x over previous
//
#include <hip/hip_runtime.h>

// PairwiseInteract via split-bf16 MFMA emulation of fp32 GEMMs.
// 8 MLPs (2->50->50->50->20) over 1024x1024 pairs, sum over actors, 2 head MLPs.
// x = x_hi + x_lo (bf16 truncation pair); D = Ah*Bh + Ah*Bl + Al*Bh in fp32 MFMA
// accumulators -> ~2^-14 relative error, well under the 0.29 abs threshold.
// One wave per block; weights live in ~160 VGPRs; activations round-trip a
// packed (hi|lo u32) LDS tile [16 rows][stride 68] between layers.

#define NOBJ 1024
#define H 50
#define F 20
#define SROW 68   // act row stride in dwords: b128 A-reads land on min-phase banking

using short8 = __attribute__((ext_vector_type(8))) short;
using v4f    = __attribute__((ext_vector_type(4))) float;

__device__ __forceinline__ unsigned pack_split(float v) {
    unsigned b  = __float_as_uint(v);
    unsigned hb = b & 0xFFFF0000u;            // hi = bf16 truncation (exact residual)
    float lo    = v - __uint_as_float(hb);    // exact in fp32
    return hb | (__float_as_uint(lo) >> 16);  // [hi16 | lo16]
}

// read 8 packed dwords (k = kt*32 + q*8 + t) and unpack to hi/lo bf16 fragments
#define READ_A(KT, AH, AL) {                                                   \
    const uint4 d0 = *(const uint4*)&act[l15 * SROW + (KT) * 32 + q * 8];      \
    const uint4 d1 = *(const uint4*)&act[l15 * SROW + (KT) * 32 + q * 8 + 4];  \
    union { unsigned u[4]; short8 s; } uh, ul;                                 \
    uh.u[0] = (d0.x >> 16) | (d0.y & 0xFFFF0000u);                             \
    uh.u[1] = (d0.z >> 16) | (d0.w & 0xFFFF0000u);                             \
    uh.u[2] = (d1.x >> 16) | (d1.y & 0xFFFF0000u);                             \
    uh.u[3] = (d1.z >> 16) | (d1.w & 0xFFFF0000u);                             \
    ul.u[0] = (d0.x & 0xFFFFu) | (d0.y << 16);                                 \
    ul.u[1] = (d0.z & 0xFFFFu) | (d0.w << 16);                                 \
    ul.u[2] = (d1.x & 0xFFFFu) | (d1.y << 16);                                 \
    ul.u[3] = (d1.z & 0xFFFFu) | (d1.w << 16);                                 \
    AH = uh.s; AL = ul.s; }

#define MFMA3(T4, AH, AL, BH, BL)                                              \
    T4 = __builtin_amdgcn_mfma_f32_16x16x32_bf16(AH, BH, T4, 0, 0, 0);         \
    T4 = __builtin_amdgcn_mfma_f32_16x16x32_bf16(AH, BL, T4, 0, 0, 0);         \
    T4 = __builtin_amdgcn_mfma_f32_16x16x32_bf16(AL, BH, T4, 0, 0, 0);

__global__ __launch_bounds__(64, 2)
void pair_kernel(const float* __restrict__ obj0, const float* __restrict__ obj1,
                 const float* __restrict__ prev0, const float* __restrict__ prev1,
                 const float* __restrict__ gW0, const float* __restrict__ gb0,
                 const float* __restrict__ gW1, const float* __restrict__ gb1,
                 const float* __restrict__ gW2, const float* __restrict__ gb2,
                 const float* __restrict__ gW3, const float* __restrict__ gb3,
                 float* __restrict__ forces)
{
    __shared__ __align__(16) unsigned act[16 * SROW];

    const int lane = threadIdx.x;       // 0..63 (single wave per block)
    const int l15  = lane & 15;
    const int q    = lane >> 4;

    const int m  = blockIdx.z;          // module 0..7
    const int a  = m >> 1;
    const int c  = m & 1;
    const int i0 = blockIdx.y * 4;      // 4 actees per wave
    const int jq = blockIdx.x;          // j-quarter (256 actors)

    const float* actor = (a == 0) ? obj0 : (a == 1) ? obj1 : (a == 2) ? prev0 : prev1;
    const float* actee = (c == 0) ? obj0 : obj1;

    // ---- layer-0 per-lane weights (lane = neuron k of layer-1 input) ----
    const float* W0 = gW0 + m * 2 * H;
    const float w0a_l = (lane < H) ? W0[lane]     : 0.f;
    const float w0b_l = (lane < H) ? W0[H + lane] : 0.f;
    const float b0_l  = (lane < H) ? gb0[m * H + lane] : 0.f;

    // ---- per-lane biases (by output column) ----
    float bias1[4], bias2[4];
#pragma unroll
    for (int nt = 0; nt < 4; ++nt) {
        int col = nt * 16 + l15;
        bias1[nt] = (col < H) ? gb1[m * H + col] : 0.f;
        bias2[nt] = (col < H) ? gb2[m * H + col] : 0.f;
    }
    const float b3a = gb3[m * F + l15];                       // l15 < 16 < 20
    const float b3b = (l15 < 4) ? gb3[m * F + 16 + l15] : 0.f;

    // ---- weight B-fragments, split bf16, resident in VGPRs ----
    // B layout: lane holds W[k][n] for n = nt*16 + (lane&15), k = kt*32 + (lane>>4)*8 + t
    short8 B1h[2][4], B1l[2][4], B2h[2][4], B2l[2][4], B3h[2][2], B3l[2][2];
    {
        const float* W1 = gW1 + m * H * H;
        const float* W2 = gW2 + m * H * H;
        const float* W3 = gW3 + m * H * F;
#pragma unroll
        for (int kt = 0; kt < 2; ++kt) {
#pragma unroll
            for (int nt = 0; nt < 4; ++nt) {
                int n = nt * 16 + l15;
#pragma unroll
                for (int t = 0; t < 8; ++t) {
                    int k = kt * 32 + q * 8 + t;
                    float w1 = (k < H && n < H) ? W1[k * H + n] : 0.f;
                    float w2 = (k < H && n < H) ? W2[k * H + n] : 0.f;
                    unsigned h1 = __float_as_uint(w1) & 0xFFFF0000u;
                    unsigned h2 = __float_as_uint(w2) & 0xFFFF0000u;
                    B1h[kt][nt][t] = (short)(h1 >> 16);
                    B2h[kt][nt][t] = (short)(h2 >> 16);
                    B1l[kt][nt][t] = (short)(__float_as_uint(w1 - __uint_as_float(h1)) >> 16);
                    B2l[kt][nt][t] = (short)(__float_as_uint(w2 - __uint_as_float(h2)) >> 16);
                }
            }
#pragma unroll
            for (int nt = 0; nt < 2; ++nt) {
                int n = nt * 16 + l15;
#pragma unroll
                for (int t = 0; t < 8; ++t) {
                    int k = kt * 32 + q * 8 + t;
                    float w3 = (k < H && n < F) ? W3[k * F + n] : 0.f;
                    unsigned h3 = __float_as_uint(w3) & 0xFFFF0000u;
                    B3h[kt][nt][t] = (short)(h3 >> 16);
                    B3l[kt][nt][t] = (short)(__float_as_uint(w3 - __uint_as_float(h3)) >> 16);
                }
            }
        }
    }

#pragma unroll 1
    for (int il = 0; il < 4; ++il) {
        const int i = i0 + il;
        const float av   = actee[i];
        const float c0_l = fmaf(av, w0b_l, b0_l);
        float fAcc0 = 0.f, fAcc1 = 0.f;

#pragma unroll 1
        for (int jt = 0; jt < 16; ++jt) {
            const int jbase = jq * 256 + jt * 16;

            // ---- layer 0 (rank-1, VALU): act[row e][col lane] ----
#pragma unroll
            for (int e = 0; e < 16; ++e) {
                float xa = actor[jbase + e];                    // wave-uniform s_load
                float v  = fmaxf(fmaf(xa, w0a_l, c0_l), 0.f);   // lanes >= 50 -> 0
                act[e * SROW + lane] = pack_split(v);
            }

            // ---- layer 1: 50(->64) x 50(->64) ----
            {
                short8 Ah0, Al0, Ah1, Al1;
                READ_A(0, Ah0, Al0);
                READ_A(1, Ah1, Al1);
                v4f acc[4];
#pragma unroll
                for (int nt = 0; nt < 4; ++nt) {
                    v4f t4 = {bias1[nt], bias1[nt], bias1[nt], bias1[nt]};
                    MFMA3(t4, Ah0, Al0, B1h[0][nt], B1l[0][nt]);
                    MFMA3(t4, Ah1, Al1, B1h[1][nt], B1l[1][nt]);
                    acc[nt] = t4;
                }
#pragma unroll
                for (int nt = 0; nt < 4; ++nt)
#pragma unroll
                    for (int r = 0; r < 4; ++r)
                        act[(q * 4 + r) * SROW + nt * 16 + l15] =
                            pack_split(fmaxf(acc[nt][r], 0.f));
            }

            // ---- layer 2 ----
            {
                short8 Ah0, Al0, Ah1, Al1;
                READ_A(0, Ah0, Al0);
                READ_A(1, Ah1, Al1);
                v4f acc[4];
#pragma unroll
                for (int nt = 0; nt < 4; ++nt) {
                    v4f t4 = {bias2[nt], bias2[nt], bias2[nt], bias2[nt]};
                    MFMA3(t4, Ah0, Al0, B2h[0][nt], B2l[0][nt]);
                    MFMA3(t4, Ah1, Al1, B2h[1][nt], B2l[1][nt]);
                    acc[nt] = t4;
                }
#pragma unroll
                for (int nt = 0; nt < 4; ++nt)
#pragma unroll
                    for (int r = 0; r < 4; ++r)
                        act[(q * 4 + r) * SROW + nt * 16 + l15] =
                            pack_split(fmaxf(acc[nt][r], 0.f));
            }

            // ---- layer 3: 50(->64) x 20(->32), no relu, row-sum over actors ----
            {
                short8 Ah0, Al0, Ah1, Al1;
                READ_A(0, Ah0, Al0);
                READ_A(1, Ah1, Al1);
#pragma unroll
                for (int nt = 0; nt < 2; ++nt) {
                    v4f t4 = {0.f, 0.f, 0.f, 0.f};
                    MFMA3(t4, Ah0, Al0, B3h[0][nt], B3l[0][nt]);
                    MFMA3(t4, Ah1, Al1, B3h[1][nt], B3l[1][nt]);
                    float s = t4[0] + t4[1] + t4[2] + t4[3];   // sum 4 rows in-lane
                    if (nt == 0) fAcc0 += s; else fAcc1 += s;
                }
            }
        }

        // ---- flush per actee i: reduce over q-groups, one atomic per (i,f) ----
        float v0 = fAcc0;
        v0 += __shfl_xor(v0, 16, 64);
        v0 += __shfl_xor(v0, 32, 64);
        float v1 = fAcc1;
        v1 += __shfl_xor(v1, 16, 64);
        v1 += __shfl_xor(v1, 32, 64);
        if (q == 0) {
            float* dst = forces + (c * NOBJ + i) * F;
            atomicAdd(dst + l15, v0 + 256.f * b3a);            // 256 rows of bias
            if (l15 < 4)
                atomicAdd(dst + 16 + l15, v1 + 256.f * b3b);
        }
    }
}

__global__ __launch_bounds__(256)
void apply_kernel(const float* __restrict__ forces,
                  const float* __restrict__ aW0, const float* __restrict__ ab0,
                  const float* __restrict__ aW1, const float* __restrict__ ab1,
                  float* __restrict__ out)
{
    const int t = blockIdx.x * 256 + threadIdx.x;   // 0..2047
    const int c = t >> 10;                          // wave-uniform
    const int i = t & 1023;

    const float* f = forces + (c * NOBJ + i) * F;
    float fin[F];
#pragma unroll
    for (int k = 0; k < F; ++k) fin[k] = f[k];

    const float* __restrict__ w0 = aW0 + c * F * H;   // (20,50)
    const float* __restrict__ b0 = ab0 + c * H;
    const float* __restrict__ w1 = aW1 + c * H;       // (50,1)
    float pred = ab1[c];
#pragma unroll
    for (int o = 0; o < H; ++o) {
        float s = b0[o];
#pragma unroll
        for (int k = 0; k < F; ++k) s = fmaf(fin[k], w0[k * H + o], s);
        pred = fmaf(fmaxf(s, 0.f), w1[o], pred);
    }
    out[t] = pred;
}

extern "C" void kernel_launch(void* const* d_in, const int* in_sizes, int n_in,
                              void* d_out, int out_size, void* d_ws, size_t ws_size,
                              hipStream_t stream) {
    const float* obj0  = (const float*)d_in[0];
    const float* obj1  = (const float*)d_in[1];
    const float* prev0 = (const float*)d_in[2];
    const float* prev1 = (const float*)d_in[3];
    const float* gW0 = (const float*)d_in[4];
    const float* gb0 = (const float*)d_in[5];
    const float* gW1 = (const float*)d_in[6];
    const float* gb1 = (const float*)d_in[7];
    const float* gW2 = (const float*)d_in[8];
    const float* gb2 = (const float*)d_in[9];
    const float* gW3 = (const float*)d_in[10];
    const float* gb3 = (const float*)d_in[11];
    const float* aW0 = (const float*)d_in[12];
    const float* ab0 = (const float*)d_in[13];
    const float* aW1 = (const float*)d_in[14];
    const float* ab1 = (const float*)d_in[15];

    float* forces = (float*)d_ws;   // [2][1024][20] fp32 accumulator
    hipMemsetAsync(forces, 0, 2 * NOBJ * F * sizeof(float), stream);

    dim3 g1(4, 256, 8);   // j-quarters x i-groups x modules
    pair_kernel<<<g1, dim3(64), 0, stream>>>(obj0, obj1, prev0, prev1,
                                             gW0, gb0, gW1, gb1, gW2, gb2, gW3, gb3,
                                             forces);

    apply_kernel<<<8, 256, 0, stream>>>(forces, aW0, ab0, aW1, ab1, (float*)d_out);
}

// Round 3
// 535.581 us; speedup vs baseline: 2.5833x; 1.1536x over previous
//
#include <hip/hip_runtime.h>

// PairwiseInteract, round 3: transposed GEMMs on 32x32x16 bf16 MFMA with
// split-bf16 (hi/lo) fp32 emulation, neuron-permuted so each layer's MFMA
// C-output slots ARE the next layer's B-fragment slots (same lane) -> the
// inter-layer transform is relu + split + v_perm only: no LDS round-trip,
// no shuffles in the main loop. Biases ride as weight row 50 against an
// injected 1.0 activation; L3 accumulates across tiles in its C operand.
// W1/W2/W3 fragments staged per-workgroup in LDS (40KB, linear b128 reads).

#define NOBJ 1024
#define H 50
#define F 20

using short8 = __attribute__((ext_vector_type(8))) short;
using v16f   = __attribute__((ext_vector_type(16))) float;

#define MFMA(A, B, C) __builtin_amdgcn_mfma_f32_32x32x16_bf16((A), (B), (C), 0, 0, 0)

__device__ __forceinline__ float trunchi(float x) {
    return __uint_as_float(__float_as_uint(x) & 0xFFFF0000u);
}
// dword = hi16(a) in low half | hi16(b) in high half
__device__ __forceinline__ unsigned pkhi(float a, float b) {
    return __builtin_amdgcn_perm(__float_as_uint(b), __float_as_uint(a), 0x07060302u);
}
__device__ __forceinline__ short8 as_s8(uint4 v) {
    union { uint4 u; short8 s; } x; x.u = v; return x.s;
}
// out-neuron at C slot (mt, tile-row l)
__device__ __forceinline__ int nu(int mt, int l) {
    return 16 * (l >> 3) + 8 * ((l >> 2) & 1) + 4 * mt + (l & 3);
}

// pack one m-tile of C output into dwords 2*MT, 2*MT+1 of the B frags
#define PACK_MT(ACC, MT, XH, XL)                                              \
    _Pragma("unroll") for (int f_ = 0; f_ < 4; ++f_) {                        \
        float r0 = fmaxf((ACC)[4 * f_ + 0], 0.f);                             \
        float r1 = fmaxf((ACC)[4 * f_ + 1], 0.f);                             \
        float r2 = fmaxf((ACC)[4 * f_ + 2], 0.f);                             \
        float r3 = fmaxf((ACC)[4 * f_ + 3], 0.f);                             \
        float l0 = r0 - trunchi(r0), l1 = r1 - trunchi(r1);                   \
        float l2 = r2 - trunchi(r2), l3 = r3 - trunchi(r3);                   \
        ((unsigned*)&(XH)[f_])[2 * (MT) + 0] = pkhi(r0, r1);                  \
        ((unsigned*)&(XH)[f_])[2 * (MT) + 1] = pkhi(r2, r3);                  \
        ((unsigned*)&(XL)[f_])[2 * (MT) + 0] = pkhi(l0, l1);                  \
        ((unsigned*)&(XL)[f_])[2 * (MT) + 1] = pkhi(l2, l3);                  \
    }

#define LDSFRAG(id) (*(const short8*)&wfrag[(id) * 64 + lane])

// hidden layer: 2 m-tiles x 4 k-frags x 3 split terms = 24 MFMA
#define LAYER_CHAIN(BASEC, XH, XL, A0, A1)                                    \
    _Pragma("unroll") for (int f_ = 0; f_ < 4; ++f_) {                        \
        short8 ah0 = LDSFRAG(((BASEC) + f_) * 2 + 0);                         \
        short8 al0 = LDSFRAG(((BASEC) + f_) * 2 + 1);                         \
        short8 ah1 = LDSFRAG(((BASEC) + 4 + f_) * 2 + 0);                     \
        short8 al1 = LDSFRAG(((BASEC) + 4 + f_) * 2 + 1);                     \
        short8 bh = as_s8((XH)[f_]), bl = as_s8((XL)[f_]);                    \
        if (f_ == 0) { A0 = MFMA(ah0, bh, zero16); A1 = MFMA(ah1, bh, zero16); } \
        else         { A0 = MFMA(ah0, bh, A0);     A1 = MFMA(ah1, bh, A1); }  \
        A0 = MFMA(ah0, bl, A0); A1 = MFMA(ah1, bl, A1);                       \
        A0 = MFMA(al0, bh, A0); A1 = MFMA(al1, bh, A1);                       \
    }

__global__ __launch_bounds__(256, 2)
void pair_kernel(const float* __restrict__ obj0, const float* __restrict__ obj1,
                 const float* __restrict__ prev0, const float* __restrict__ prev1,
                 const float* __restrict__ gW0, const float* __restrict__ gb0,
                 const float* __restrict__ gW1, const float* __restrict__ gb1,
                 const float* __restrict__ gW2, const float* __restrict__ gb2,
                 const float* __restrict__ gW3, const float* __restrict__ gb3,
                 float* __restrict__ forces)
{
    // 40 pre-packed A-fragments (L1:0..15, L2:16..31, L3:32..39), 1KB each
    __shared__ uint4 wfrag[40 * 64];

    const int w    = threadIdx.x >> 6;   // wave 0..3
    const int lane = threadIdx.x & 63;
    const int h    = lane >> 5;          // half-wave
    const int l31  = lane & 31;

    const int m = blockIdx.y;            // module
    const int a = m >> 1, c = m & 1;

    const float* actor = (a == 0) ? obj0 : (a == 1) ? obj1 : (a == 2) ? prev0 : prev1;
    const float* actee = (c == 0) ? obj0 : obj1;

    // ---- stage W1/W2/W3 split-bf16 A-fragments into LDS (once per wg) ----
    for (int combo = w; combo < 20; combo += 4) {
        const int layer = (combo < 8) ? 1 : (combo < 16) ? 2 : 3;
        const int rel   = (layer == 1) ? combo : (layer == 2) ? combo - 8 : combo - 16;
        const int mt    = (layer == 3) ? 0 : (rel >> 2);
        const int f     = (layer == 3) ? rel : (rel & 3);
        const float* W; const float* b; int ncols, col;
        if (layer == 1)      { W = gW1 + m * H * H; b = gb1 + m * H; ncols = H; col = nu(mt, l31); }
        else if (layer == 2) { W = gW2 + m * H * H; b = gb2 + m * H; ncols = H; col = nu(mt, l31); }
        else                 { W = gW3 + m * H * F; b = gb3 + m * F; ncols = F; col = l31; }
        unsigned hs[8], ls[8];
#pragma unroll
        for (int j = 0; j < 8; ++j) {
            const int k = 16 * f + 8 * h + j;
            float wv = 0.f;
            if (col < ncols) {
                if (k < H) wv = W[k * ncols + col];
                else if (k == H) wv = b[col];          // bias row
            }
            unsigned uh = __float_as_uint(wv) & 0xFFFF0000u;
            float lof = wv - __uint_as_float(uh);
            hs[j] = uh;
            ls[j] = __float_as_uint(lof) & 0xFFFF0000u;
        }
        uint4 hi, lo;
        hi.x = (hs[0] >> 16) | hs[1]; hi.y = (hs[2] >> 16) | hs[3];
        hi.z = (hs[4] >> 16) | hs[5]; hi.w = (hs[6] >> 16) | hs[7];
        lo.x = (ls[0] >> 16) | ls[1]; lo.y = (ls[2] >> 16) | ls[3];
        lo.z = (ls[4] >> 16) | ls[5]; lo.w = (ls[6] >> 16) | ls[7];
        wfrag[(combo * 2 + 0) * 64 + lane] = hi;
        wfrag[(combo * 2 + 1) * 64 + lane] = lo;
    }

    // ---- W0ext A-fragments in registers (rows: w0a, w0b, b0, 0...) ----
    short8 W0h[2], W0l[2];
    {
        const float* W0p = gW0 + m * 2 * H;
        const float* b0p = gb0 + m * H;
#pragma unroll
        for (int mt = 0; mt < 2; ++mt) {
            const int col = nu(mt, l31);
            float v0 = 0.f, v1 = 0.f, v2 = 0.f;
            if (h == 0 && col < H) { v0 = W0p[col]; v1 = W0p[H + col]; v2 = b0p[col]; }
            float q0 = v0 - trunchi(v0), q1 = v1 - trunchi(v1), q2 = v2 - trunchi(v2);
            uint4 hi, lo;
            hi.x = pkhi(v0, v1); hi.y = pkhi(v2, 0.f); hi.z = 0u; hi.w = 0u;
            lo.x = pkhi(q0, q1); lo.y = pkhi(q2, 0.f); lo.z = 0u; lo.w = 0u;
            W0h[mt] = as_s8(hi); W0l[mt] = as_s8(lo);
        }
    }
    __syncthreads();

    // ---- per-wave work: one actee, one j-half (16 tiles of 32 pairs) ----
    const int i  = blockIdx.x * 2 + (w >> 1);
    const int jh = w & 1;
    const float av  = actee[i];
    const float avl = av - trunchi(av);
    const unsigned inj = (h == 0) ? 0x00003F80u : 0u;   // 1.0bf16 into slot k=50 (f=3,j=2)

    const v16f zero16 = (v16f)0.0f;
    v16f fAcc = (v16f)0.0f;

#pragma unroll 1
    for (int jt = 0; jt < 16; ++jt) {
        const int jbase = jh * 512 + jt * 32;
        const float xa  = actor[jbase + l31];
        const float xal = xa - trunchi(xa);

        // L0 B operand: k-slots (h=0): 0=actor, 1=actee, 2=1.0(bias), rest pad
        uint4 b0h4, b0l4;
        b0h4.x = pkhi(xa, av);   b0h4.y = 0x00003F80u; b0h4.z = 0u; b0h4.w = 0u;
        b0l4.x = pkhi(xal, avl); b0l4.y = 0u;          b0l4.z = 0u; b0l4.w = 0u;
        const short8 B0h = as_s8(b0h4), B0l = as_s8(b0l4);

        // ---- L0: 6 MFMA ----
        v16f a0, a1;
        a0 = MFMA(W0h[0], B0h, zero16); a1 = MFMA(W0h[1], B0h, zero16);
        a0 = MFMA(W0h[0], B0l, a0);     a1 = MFMA(W0h[1], B0l, a1);
        a0 = MFMA(W0l[0], B0h, a0);     a1 = MFMA(W0l[1], B0h, a1);

        uint4 X1h[4], X1l[4];
        PACK_MT(a0, 0, X1h, X1l); PACK_MT(a1, 1, X1h, X1l);
        X1h[3].y |= inj;

        // ---- L1: 24 MFMA ----
        LAYER_CHAIN(0, X1h, X1l, a0, a1);
        uint4 X2h[4], X2l[4];
        PACK_MT(a0, 0, X2h, X2l); PACK_MT(a1, 1, X2h, X2l);
        X2h[3].y |= inj;

        // ---- L2: 24 MFMA ----
        LAYER_CHAIN(8, X2h, X2l, a0, a1);
        uint4 X3h[4], X3l[4];
        PACK_MT(a0, 0, X3h, X3l); PACK_MT(a1, 1, X3h, X3l);
        X3h[3].y |= inj;

        // ---- L3: 12 MFMA, accumulate across tiles in C ----
#pragma unroll
        for (int f = 0; f < 4; ++f) {
            short8 ah = LDSFRAG((16 + f) * 2 + 0);
            short8 al = LDSFRAG((16 + f) * 2 + 1);
            short8 bh = as_s8(X3h[f]), bl = as_s8(X3l[f]);
            fAcc = MFMA(ah, bh, fAcc);
            fAcc = MFMA(ah, bl, fAcc);
            fAcc = MFMA(al, bh, fAcc);
        }
    }

    // ---- reduce over pairs (columns) and commit ----
    float* dst = forces + (c * NOBJ + i) * F;
#pragma unroll
    for (int r = 0; r < 16; ++r) {
        float v = fAcc[r];
        v += __shfl_xor(v, 1);
        v += __shfl_xor(v, 2);
        v += __shfl_xor(v, 4);
        v += __shfl_xor(v, 8);
        v += __shfl_xor(v, 16);
        const int row = (r & 3) + 8 * (r >> 2) + 4 * h;   // natural L3 out-feature
        if (l31 == 0 && row < F) atomicAdd(dst + row, v);
    }
}

__global__ __launch_bounds__(256)
void apply_kernel(const float* __restrict__ forces,
                  const float* __restrict__ aW0, const float* __restrict__ ab0,
                  const float* __restrict__ aW1, const float* __restrict__ ab1,
                  float* __restrict__ out)
{
    const int t = blockIdx.x * 256 + threadIdx.x;   // 0..2047
    const int c = t >> 10;                          // wave-uniform
    const int i = t & 1023;

    const float* f = forces + (c * NOBJ + i) * F;
    float fin[F];
#pragma unroll
    for (int k = 0; k < F; ++k) fin[k] = f[k];

    const float* __restrict__ w0 = aW0 + c * F * H;   // (20,50)
    const float* __restrict__ b0 = ab0 + c * H;
    const float* __restrict__ w1 = aW1 + c * H;       // (50,1)
    float pred = ab1[c];
#pragma unroll
    for (int o = 0; o < H; ++o) {
        float s = b0[o];
#pragma unroll
        for (int k = 0; k < F; ++k) s = fmaf(fin[k], w0[k * H + o], s);
        pred = fmaf(fmaxf(s, 0.f), w1[o], pred);
    }
    out[t] = pred;
}

extern "C" void kernel_launch(void* const* d_in, const int* in_sizes, int n_in,
                              void* d_out, int out_size, void* d_ws, size_t ws_size,
                              hipStream_t stream) {
    const float* obj0  = (const float*)d_in[0];
    const float* obj1  = (const float*)d_in[1];
    const float* prev0 = (const float*)d_in[2];
    const float* prev1 = (const float*)d_in[3];
    const float* gW0 = (const float*)d_in[4];
    const float* gb0 = (const float*)d_in[5];
    const float* gW1 = (const float*)d_in[6];
    const float* gb1 = (const float*)d_in[7];
    const float* gW2 = (const float*)d_in[8];
    const float* gb2 = (const float*)d_in[9];
    const float* gW3 = (const float*)d_in[10];
    const float* gb3 = (const float*)d_in[11];
    const float* aW0 = (const float*)d_in[12];
    const float* ab0 = (const float*)d_in[13];
    const float* aW1 = (const float*)d_in[14];
    const float* ab1 = (const float*)d_in[15];

    float* forces = (float*)d_ws;   // [2][1024][20] fp32 accumulator
    hipMemsetAsync(forces, 0, 2 * NOBJ * F * sizeof(float), stream);

    dim3 grid(NOBJ / 2, 8);   // i-groups x modules; 4 waves/wg: 2 actees x 2 j-halves
    pair_kernel<<<grid, 256, 0, stream>>>(obj0, obj1, prev0, prev1,
                                          gW0, gb0, gW1, gb1, gW2, gb2, gW3, gb3,
                                          forces);

    apply_kernel<<<8, 256, 0, stream>>>(forces, aW0, ab0, aW1, ab1, (float*)d_out);
}